// Round 23
// baseline (283.068 us; speedup 1.0000x reference)
//
#include <hip/hip_runtime.h>
#include <hip/hip_bf16.h>
#include <stdint.h>

// ---- All intermediates live inside d_out (16,777,216 f32; 256 slots x 65536 f32).
// Slot q (q=b*64+co): [0,4096) feat plane q ; [4096,8192) cat plane p (p<256, p&255==q)
// [8192,12288) cat plane p (p>=256) ; [12288] mean ; [12289] att ;
// [16384,24576) f64 x1_hi plane q ; [25600,26112) wT chunks ; [26624,27136) wdT64 chunks (f64).
__device__ __forceinline__ float* catp(float* o, int p) {
    return o + (size_t)(p & 255) * 65536 + 4096 + ((p >> 8) << 12);
}
__device__ __forceinline__ double* x1hp(float* o, int q) {
    return (double*)(o + (size_t)q * 65536 + 16384);
}
__device__ __forceinline__ float wtv(const float* o, int kk, int co) {
    return o[(size_t)(kk >> 3) * 65536 + 25600 + (kk & 7) * 64 + co];
}
__device__ __forceinline__ double* wd64p(float* o, int k) {   // + co
    return (double*)(o + (size_t)(k >> 2) * 65536 + 26624) + (k & 3) * 64;
}

// ---------------- K0: w1 -> wT[kk][co] (f32); wd -> wdT64[k][co] (f64)
__global__ __launch_bounds__(256) void k0_wtrans(const float* __restrict__ w1, const float* __restrict__ wd,
                                                 float* __restrict__ o) {
    int idx = blockIdx.x * 256 + threadIdx.x;
    if (idx < 73728) {
        int co = idx & 63, kk = idx >> 6;
        o[(size_t)(kk >> 3) * 65536 + 25600 + (kk & 7) * 64 + co] = w1[co * 1152 + kk];
    } else if (idx < 139264) {
        int j = idx - 73728;
        int co = j & 63, k = j >> 6;
        wd64p(o, k)[co] = (double)wd[co * 1024 + k];
    }
}

// ---------------- K1: 4x4/stride-4 conv + BN + ReLU as f64 register-blocked GEMM
// grid: 512 = (b,i,jh); block 256; thread = 4co x 2j. Double-buffered LDS (48KB) +
// register prefetch; ONE barrier/panel. Bit-identical outputs.
__global__ __launch_bounds__(256) void k1_convds(
    const float* __restrict__ x, const float* __restrict__ bd,
    const float* __restrict__ g, const float* __restrict__ be,
    const float* __restrict__ m, const float* __restrict__ v,
    float* __restrict__ o)
{
    __shared__ __align__(16) double wlds[2][32 * 64];
    __shared__ __align__(16) double xlds[2][32 * 32];
    int blk = blockIdx.x;
    int jh = blk & 1, i = (blk >> 1) & 63, b = blk >> 7;
    int t = threadIdx.x;
    int tj = t & 15, tc = t >> 4;
    int s_f4j = t & 31, s_ky = (t >> 5) & 3, s_ciL = t >> 7;
    int s_kq = (s_ciL * 16 + s_ky * 4) * 32 + s_f4j;

    double acc[4][2];
    #pragma unroll
    for (int c = 0; c < 4; ++c) { acc[c][0] = 0.0; acc[c][1] = 0.0; }

    double wreg[8];
    float4 xreg;
    #pragma unroll
    for (int u = 0; u < 8; ++u) {
        int idx = t + u * 256;
        wreg[u] = wd64p(o, (idx >> 6))[idx & 63];
    }
    xreg = *(const float4*)(x + (((size_t)(b * 64 + s_ciL) * 256 + (i * 4 + s_ky)) * 256 + jh * 128 + s_f4j * 4));
    #pragma unroll
    for (int u = 0; u < 8; ++u) {
        int idx = t + u * 256;
        wlds[0][(idx >> 6) * 64 + (idx & 63)] = wreg[u];
    }
    xlds[0][s_kq]      = (double)xreg.x;
    xlds[0][s_kq + 32] = (double)xreg.y;
    xlds[0][s_kq + 64] = (double)xreg.z;
    xlds[0][s_kq + 96] = (double)xreg.w;
    __syncthreads();

    for (int p = 0; p < 32; ++p) {
        int cur = p & 1;
        if (p + 1 < 32) {
            #pragma unroll
            for (int u = 0; u < 8; ++u) {
                int idx = t + u * 256;
                wreg[u] = wd64p(o, (p + 1) * 32 + (idx >> 6))[idx & 63];
            }
            xreg = *(const float4*)(x + (((size_t)(b * 64 + (p + 1) * 2 + s_ciL) * 256 + (i * 4 + s_ky)) * 256 + jh * 128 + s_f4j * 4));
        }
        const double* wb = wlds[cur];
        const double* xb = xlds[cur];
        #pragma unroll
        for (int ciL = 0; ciL < 2; ++ciL) {
            #pragma unroll
            for (int ky = 0; ky < 4; ++ky) {
                int kq = ciL * 16 + ky * 4;
                double w_[4][4], x_[4][2];
                #pragma unroll
                for (int kx = 0; kx < 4; ++kx) {
                    const double* wp = wb + (kq + kx) * 64;
                    const double* xp = xb + (kq + kx) * 32;
                    double2 wa0 = *(const double2*)(wp + tc * 2);
                    double2 wa1 = *(const double2*)(wp + tc * 2 + 32);
                    double2 xa0 = *(const double2*)(xp + tj * 2);
                    w_[kx][0] = wa0.x; w_[kx][1] = wa0.y; w_[kx][2] = wa1.x; w_[kx][3] = wa1.y;
                    x_[kx][0] = xa0.x; x_[kx][1] = xa0.y;
                }
                #pragma unroll
                for (int c = 0; c < 4; ++c)
                    #pragma unroll
                    for (int jj = 0; jj < 2; ++jj)
                        acc[c][jj] = fma(w_[0][c], x_[0][jj],
                                     fma(w_[1][c], x_[1][jj],
                                     fma(w_[2][c], x_[2][jj],
                                     fma(w_[3][c], x_[3][jj], acc[c][jj]))));
            }
        }
        if (p + 1 < 32) {
            int nxt = (p + 1) & 1;
            #pragma unroll
            for (int u = 0; u < 8; ++u) {
                int idx = t + u * 256;
                wlds[nxt][(idx >> 6) * 64 + (idx & 63)] = wreg[u];
            }
            xlds[nxt][s_kq]      = (double)xreg.x;
            xlds[nxt][s_kq + 32] = (double)xreg.y;
            xlds[nxt][s_kq + 64] = (double)xreg.z;
            xlds[nxt][s_kq + 96] = (double)xreg.w;
            __syncthreads();
        }
    }
    #pragma unroll
    for (int c = 0; c < 4; ++c) {
        int co = ((c >> 1) << 5) + tc * 2 + (c & 1);
        double sc = (double)g[co] / sqrt((double)v[co] + 1e-5);
        double sh = (double)bd[co] - (double)m[co];
        double bb = (double)be[co];
        double o0v = fmax(0.0, (acc[c][0] + sh) * sc + bb);
        double o1v = fmax(0.0, (acc[c][1] + sh) * sc + bb);
        int pos0 = i * 64 + jh * 32 + tj * 2;
        float* cp = catp(o, b * 128 + co);
        *(float2*)(cp + pos0) = make_float2((float)o0v, (float)o1v);
        double* xh = x1hp(o, b * 64 + co);
        *(double2*)(xh + pos0) = make_double2(o0v, o1v);
    }
}

// ---------------- K2: windowed d^2 (f64, register-accumulated) -> top-9 -> f32 gather. block 512.
// 8 stages of 8 channels (R20-measured config).
__global__ __launch_bounds__(512) void k2_feat(float* __restrict__ o)
{
    __shared__ __align__(16) char smem[29568];   // tile_d[56][66] f64 | d2s[64*50] f64 | tileq[56][68] f32
    __shared__ double sqd[7 * 64];
    __shared__ int sels[64 * 9];
    double* tile_d = (double*)smem;
    double* d2s = (double*)smem;
    float* tileq = (float*)smem;
    int blk = blockIdx.x;
    int b = blk >> 6, i = blk & 63;
    int t = threadIdx.x;
    int lane = t & 63, wv = t >> 6;

    double dacc[7];
    #pragma unroll
    for (int k = 0; k < 7; ++k) dacc[k] = 0.0;
    double sq_own = 0.0;

    for (int q = 0; q < 8; ++q) {
        __syncthreads();
        for (int s = t; s < 1792; s += 512) {
            int rc = s >> 5, c2 = s & 31;
            int r = rc >> 3, c = rc & 7;
            int gr = i - 3 + r;
            if (gr >= 0 && gr <= 63) {
                const double* src = x1hp(o, b * 64 + q * 8 + c);
                *(double2*)(tile_d + rc * 66 + c2 * 2) = *(const double2*)(src + gr * 64 + c2 * 2);
            }
        }
        __syncthreads();
        if (t < 448) {
            int r = t >> 6, col = t & 63;
            int gr = i - 3 + r;
            if (gr >= 0 && gr <= 63) {
                double s = 0.0;
                #pragma unroll
                for (int c = 0; c < 8; ++c) {
                    double xv = tile_d[(r * 8 + c) * 66 + col];
                    s = fma(xv, xv, s);
                }
                sq_own += s;
            }
        }
        double xlq[8];
        #pragma unroll
        for (int c = 0; c < 8; ++c) xlq[c] = tile_d[(24 + c) * 66 + lane];
        #pragma unroll
        for (int k = 0; k < 7; ++k) {
            int oo = wv + 8 * k;
            if (oo < 49) {
                int oi = oo / 7 - 3, oj = oo % 7 - 3;
                int mi = i + oi, mj = lane + oj;
                if (mi >= 0 && mi <= 63 && mj >= 0 && mj <= 63) {
                    int r = oi + 3;
                    double dot = 0.0;
                    #pragma unroll
                    for (int c = 0; c < 8; ++c) dot = fma(xlq[c], tile_d[(r * 8 + c) * 66 + mj], dot);
                    dacc[k] += dot;
                }
            }
        }
    }
    __syncthreads();
    if (t < 448) sqd[t] = sq_own;
    __syncthreads();
    #pragma unroll
    for (int k = 0; k < 7; ++k) {
        int oo = wv + 8 * k;
        if (oo < 49) {
            int oi = oo / 7 - 3, oj = oo % 7 - 3;
            int mi = i + oi, mj = lane + oj;
            double d2 = -1e300;
            if (mi >= 0 && mi <= 63 && mj >= 0 && mj <= 63)
                d2 = sqd[192 + lane] + sqd[(oi + 3) * 64 + mj] - 2.0 * dacc[k];
            d2s[lane * 50 + oo] = d2;
        }
    }
    __syncthreads();
    if (wv == 0) {
        unsigned long long mask = 0ull;
        for (int k = 0; k < 9; ++k) {
            double best = -1e308; int bi = 0;
            for (int oo = 0; oo < 49; ++oo) {
                if ((mask >> oo) & 1ull) continue;
                double vv = d2s[lane * 50 + oo];
                if (vv > best) { best = vv; bi = oo; }
            }
            mask |= (1ull << bi);
            sels[lane * 9 + k] = bi;
        }
    }
    __syncthreads();
    int rk[9], cj[9];
    #pragma unroll
    for (int k = 0; k < 9; ++k) {
        int oo = sels[lane * 9 + k];
        rk[k] = oo / 7;
        cj[k] = lane + (oo % 7) - 3;
    }
    for (int q = 0; q < 8; ++q) {
        __syncthreads();
        for (int s = t; s < 896; s += 512) {
            int rc = s >> 4, x4 = s & 15;
            int r = rc >> 3, c = rc & 7;
            int gr = i - 3 + r;
            if (gr >= 0 && gr <= 63)
                *(float4*)(tileq + rc * 68 + x4 * 4) =
                    *(const float4*)(catp(o, b * 128 + q * 8 + c) + gr * 64 + x4 * 4);
        }
        __syncthreads();
        {
            int c = wv;
            float s = 0.f;
            #pragma unroll
            for (int k = 0; k < 9; ++k) s += tileq[(rk[k] * 8 + c) * 68 + cj[k]];
            float outv = s * (1.f / 9.f) - tileq[(24 + c) * 68 + lane];
            catp(o, b * 128 + 64 + q * 8 + c)[i * 64 + lane] = outv;
        }
    }
}

// ---------------- K3: 3x3 conv (128->64) + BN + ReLU, double-buffered LDS + register prefetch
// grid: 512 = (b,i,jh); block 512 (co=t&63, jg=t>>6; cols jh*32+jg*4+{0..3}).
// LDS 43.5KB (2 bufs); 16 stages of 8 ci; ONE barrier/stage. Bit-identical feat.
__global__ __launch_bounds__(512) void k3_conv(
    float* __restrict__ o, const float* __restrict__ b1,
    const float* __restrict__ g, const float* __restrict__ be,
    const float* __restrict__ m, const float* __restrict__ v)
{
    __shared__ __align__(16) float wlds[2][8 * 9 * 64];   // 2x18KB
    __shared__ __align__(16) float xlds[2][3 * 8 * 40];   // 2x3.75KB
    int blk = blockIdx.x;
    int jh = blk & 1, i = (blk >> 1) & 63, b = blk >> 7;
    int t = threadIdx.x;
    int co = t & 63, jg = t >> 6;
    float acc0 = 0.f, acc1 = 0.f, acc2 = 0.f, acc3 = 0.f;
    const float4 z4 = make_float4(0.f, 0.f, 0.f, 0.f);
    // fixed staging assignment
    bool xact = t < 240;
    int x_x4 = t % 10, x_rc = t / 10;
    int x_ry = x_rc >> 3;
    int x_cl = x_rc & 7;
    int x_gr = i - 1 + x_ry;
    int x_col0 = jh * 32 - 4 + x_x4 * 4;
    bool x_ok = xact && x_gr >= 0 && x_gr <= 63 && x_col0 >= 0 && x_col0 <= 60;

    float wreg[9];
    float4 xreg = z4;
    // prologue: stage 0
    #pragma unroll
    for (int u = 0; u < 9; ++u) {
        int idx = t + u * 512;
        wreg[u] = wtv(o, (idx >> 6), idx & 63);
    }
    if (x_ok) xreg = *(const float4*)(catp(o, b * 128 + x_cl) + x_gr * 64 + x_col0);
    #pragma unroll
    for (int u = 0; u < 9; ++u) {
        int idx = t + u * 512;
        wlds[0][idx] = wreg[u];
    }
    if (xact) *(float4*)(&xlds[0][x_rc * 40 + x_x4 * 4]) = x_ok ? xreg : z4;
    __syncthreads();

    for (int st = 0; st < 16; ++st) {
        int cur = st & 1;
        if (st + 1 < 16) {
            #pragma unroll
            for (int u = 0; u < 9; ++u) {
                int idx = t + u * 512;
                wreg[u] = wtv(o, (st + 1) * 72 + (idx >> 6), idx & 63);
            }
            if (x_ok) xreg = *(const float4*)(catp(o, b * 128 + (st + 1) * 8 + x_cl) + x_gr * 64 + x_col0);
        }
        const float* wb = wlds[cur];
        const float* xb = xlds[cur];
        for (int cl = 0; cl < 8; ++cl) {
            #pragma unroll
            for (int ry = 0; ry < 3; ++ry) {
                float w0  = wb[(cl * 9 + ry * 3 + 0) * 64 + co];
                float w1f = wb[(cl * 9 + ry * 3 + 1) * 64 + co];
                float w2  = wb[(cl * 9 + ry * 3 + 2) * 64 + co];
                const float* xr = xb + (ry * 8 + cl) * 40 + jg * 4;
                float4 q0 = *(const float4*)(xr);
                float4 q1 = *(const float4*)(xr + 4);
                float4 q2 = *(const float4*)(xr + 8);
                float xv[12] = { q0.x,q0.y,q0.z,q0.w, q1.x,q1.y,q1.z,q1.w, q2.x,q2.y,q2.z,q2.w };
                acc0 = fmaf(w0, xv[3], fmaf(w1f, xv[4], fmaf(w2, xv[5], acc0)));
                acc1 = fmaf(w0, xv[4], fmaf(w1f, xv[5], fmaf(w2, xv[6], acc1)));
                acc2 = fmaf(w0, xv[5], fmaf(w1f, xv[6], fmaf(w2, xv[7], acc2)));
                acc3 = fmaf(w0, xv[6], fmaf(w1f, xv[7], fmaf(w2, xv[8], acc3)));
            }
        }
        if (st + 1 < 16) {
            int nxt = (st + 1) & 1;
            #pragma unroll
            for (int u = 0; u < 9; ++u) {
                int idx = t + u * 512;
                wlds[nxt][idx] = wreg[u];
            }
            if (xact) *(float4*)(&xlds[nxt][x_rc * 40 + x_x4 * 4]) = x_ok ? xreg : z4;
            __syncthreads();
        }
    }
    float sc = g[co] * rsqrtf(v[co] + 1e-5f);
    float sh = b1[co] - m[co];
    float bb = be[co];
    float4 ov;
    ov.x = fmaxf(0.f, fmaf(acc0 + sh, sc, bb));
    ov.y = fmaxf(0.f, fmaf(acc1 + sh, sc, bb));
    ov.z = fmaxf(0.f, fmaf(acc2 + sh, sc, bb));
    ov.w = fmaxf(0.f, fmaf(acc3 + sh, sc, bb));
    *(float4*)(o + (size_t)(b * 64 + co) * 65536 + i * 64 + jh * 32 + jg * 4) = ov;
}

// ---------------- K4a: per-plane spatial mean -> slot[12288]
__global__ __launch_bounds__(256) void k4_mean(float* __restrict__ o) {
    int q = blockIdx.x, t = threadIdx.x;
    const float* p = o + (size_t)q * 65536;
    float s = 0.f;
    for (int k = t; k < 4096; k += 256) s += p[k];
    #pragma unroll
    for (int off = 32; off > 0; off >>= 1) s += __shfl_down(s, off, 64);
    __shared__ float red[4];
    if ((t & 63) == 0) red[t >> 6] = s;
    __syncthreads();
    if (t == 0) o[(size_t)q * 65536 + 12288] = (red[0] + red[1] + red[2] + red[3]) * (1.f / 4096.f);
}

// ---------------- K4b: 1x1 conv + BN + sigmoid -> slot[12289]
__global__ __launch_bounds__(256) void k4_att(float* __restrict__ o, const float* __restrict__ wa,
    const float* __restrict__ g, const float* __restrict__ be, const float* __restrict__ m, const float* __restrict__ v) {
    int t = threadIdx.x;
    int b = t >> 6, co = t & 63;
    const float* wr = wa + co * 64;
    float s = 0.f;
    for (int ci = 0; ci < 64; ++ci) s = fmaf(wr[ci], o[(size_t)(b * 64 + ci) * 65536 + 12288], s);
    float sc = g[co] * rsqrtf(v[co] + 1e-5f);
    float y = fmaf(s - m[co], sc, be[co]);
    o[(size_t)t * 65536 + 12289] = 1.f / (1.f + expf(-y));
}

// ---------------- K5: out = bilinear_x4(feat)*att, in place over own slot. block 1024.
__global__ __launch_bounds__(1024) void k5_up(float* __restrict__ o) {
    __shared__ __align__(16) float fplane[4096];
    int bc = blockIdx.x;
    int t = threadIdx.x;
    float* slot = o + (size_t)bc * 65536;
    *(float4*)(fplane + t * 4) = *(const float4*)(slot + t * 4);
    float att = slot[12289];
    __syncthreads();
    int ox = t & 255, oyc = t >> 8;
    float fx = ox * 0.25f - 0.375f;
    int ix = (int)floorf(fx);
    float wx = fx - (float)ix;
    int x0 = ix < 0 ? 0 : ix;
    int x1 = (ix + 1 > 63) ? 63 : ix + 1;
    for (int oy = oyc * 64; oy < oyc * 64 + 64; ++oy) {
        float fy = oy * 0.25f - 0.375f;
        int iy = (int)floorf(fy);
        float wy = fy - (float)iy;
        int y0 = iy < 0 ? 0 : iy;
        int y1 = (iy + 1 > 63) ? 63 : iy + 1;
        float a  = fplane[y0 * 64 + x0], b_ = fplane[y0 * 64 + x1];
        float c_ = fplane[y1 * 64 + x0], d_ = fplane[y1 * 64 + x1];
        float top = a + wx * (b_ - a);
        float bot = c_ + wx * (d_ - c_);
        float val = (top + wy * (bot - top)) * att;
        slot[oy * 256 + ox] = val;
    }
}

extern "C" void kernel_launch(void* const* d_in, const int* in_sizes, int n_in,
                              void* d_out, int out_size, void* d_ws, size_t ws_size,
                              hipStream_t stream) {
    const float* x     = (const float*)d_in[0];
    const float* wd    = (const float*)d_in[1];
    const float* bd    = (const float*)d_in[2];
    const float* bnd_g = (const float*)d_in[3];
    const float* bnd_b = (const float*)d_in[4];
    const float* bnd_m = (const float*)d_in[5];
    const float* bnd_v = (const float*)d_in[6];
    const float* w1    = (const float*)d_in[7];
    const float* b1    = (const float*)d_in[8];
    const float* bn1_g = (const float*)d_in[9];
    const float* bn1_b = (const float*)d_in[10];
    const float* bn1_m = (const float*)d_in[11];
    const float* bn1_v = (const float*)d_in[12];
    const float* wa    = (const float*)d_in[13];
    const float* bna_g = (const float*)d_in[14];
    const float* bna_b = (const float*)d_in[15];
    const float* bna_m = (const float*)d_in[16];
    const float* bna_v = (const float*)d_in[17];

    float* o = (float*)d_out;

    hipLaunchKernelGGL(k0_wtrans, dim3(544), dim3(256), 0, stream, w1, wd, o);
    hipLaunchKernelGGL(k1_convds, dim3(512), dim3(256), 0, stream,
                       x, bd, bnd_g, bnd_b, bnd_m, bnd_v, o);
    hipLaunchKernelGGL(k2_feat, dim3(256), dim3(512), 0, stream, o);
    hipLaunchKernelGGL(k3_conv, dim3(512), dim3(512), 0, stream,
                       o, b1, bn1_g, bn1_b, bn1_m, bn1_v);
    hipLaunchKernelGGL(k4_mean, dim3(256), dim3(256), 0, stream, o);
    hipLaunchKernelGGL(k4_att, dim3(1), dim3(256), 0, stream,
                       o, wa, bna_g, bna_b, bna_m, bna_v);
    hipLaunchKernelGGL(k5_up, dim3(256), dim3(1024), 0, stream, o);
}

// Round 24
// 235.836 us; speedup vs baseline: 1.2003x; 1.2003x over previous
//
#include <hip/hip_runtime.h>
#include <hip/hip_bf16.h>
#include <stdint.h>

// ---- All intermediates live inside d_out (16,777,216 f32; 256 slots x 65536 f32).
// Slot q (q=b*64+co): [0,4096) feat plane q ; [4096,8192) cat plane p (p<256, p&255==q)
// [8192,12288) cat plane p (p>=256) ; [12288] mean ;
// [16384,24576) f64 x1_hi plane q ; [25600,26112) wT chunks ; [26624,27136) wdT64 chunks (f64).
__device__ __forceinline__ float* catp(float* o, int p) {
    return o + (size_t)(p & 255) * 65536 + 4096 + ((p >> 8) << 12);
}
__device__ __forceinline__ double* x1hp(float* o, int q) {
    return (double*)(o + (size_t)q * 65536 + 16384);
}
__device__ __forceinline__ float wtv(const float* o, int kk, int co) {
    return o[(size_t)(kk >> 3) * 65536 + 25600 + (kk & 7) * 64 + co];
}
__device__ __forceinline__ double* wd64p(float* o, int k) {   // + co
    return (double*)(o + (size_t)(k >> 2) * 65536 + 26624) + (k & 3) * 64;
}

// ---------------- K0: w1 -> wT[kk][co] (f32); wd -> wdT64[k][co] (f64)
__global__ __launch_bounds__(256) void k0_wtrans(const float* __restrict__ w1, const float* __restrict__ wd,
                                                 float* __restrict__ o) {
    int idx = blockIdx.x * 256 + threadIdx.x;
    if (idx < 73728) {
        int co = idx & 63, kk = idx >> 6;
        o[(size_t)(kk >> 3) * 65536 + 25600 + (kk & 7) * 64 + co] = w1[co * 1152 + kk];
    } else if (idx < 139264) {
        int j = idx - 73728;
        int co = j & 63, k = j >> 6;
        wd64p(o, k)[co] = (double)wd[co * 1024 + k];
    }
}

// ---------------- K1: 4x4/stride-4 conv + BN + ReLU as f64 register-blocked GEMM
// grid: 512 = (b,i,jh); block 256; thread = 4co x 2j. Double-buffered LDS (48KB) +
// register prefetch; ONE barrier/panel. Bit-identical outputs.
__global__ __launch_bounds__(256) void k1_convds(
    const float* __restrict__ x, const float* __restrict__ bd,
    const float* __restrict__ g, const float* __restrict__ be,
    const float* __restrict__ m, const float* __restrict__ v,
    float* __restrict__ o)
{
    __shared__ __align__(16) double wlds[2][32 * 64];
    __shared__ __align__(16) double xlds[2][32 * 32];
    int blk = blockIdx.x;
    int jh = blk & 1, i = (blk >> 1) & 63, b = blk >> 7;
    int t = threadIdx.x;
    int tj = t & 15, tc = t >> 4;
    int s_f4j = t & 31, s_ky = (t >> 5) & 3, s_ciL = t >> 7;
    int s_kq = (s_ciL * 16 + s_ky * 4) * 32 + s_f4j;

    double acc[4][2];
    #pragma unroll
    for (int c = 0; c < 4; ++c) { acc[c][0] = 0.0; acc[c][1] = 0.0; }

    double wreg[8];
    float4 xreg;
    #pragma unroll
    for (int u = 0; u < 8; ++u) {
        int idx = t + u * 256;
        wreg[u] = wd64p(o, (idx >> 6))[idx & 63];
    }
    xreg = *(const float4*)(x + (((size_t)(b * 64 + s_ciL) * 256 + (i * 4 + s_ky)) * 256 + jh * 128 + s_f4j * 4));
    #pragma unroll
    for (int u = 0; u < 8; ++u) {
        int idx = t + u * 256;
        wlds[0][(idx >> 6) * 64 + (idx & 63)] = wreg[u];
    }
    xlds[0][s_kq]      = (double)xreg.x;
    xlds[0][s_kq + 32] = (double)xreg.y;
    xlds[0][s_kq + 64] = (double)xreg.z;
    xlds[0][s_kq + 96] = (double)xreg.w;
    __syncthreads();

    for (int p = 0; p < 32; ++p) {
        int cur = p & 1;
        if (p + 1 < 32) {
            #pragma unroll
            for (int u = 0; u < 8; ++u) {
                int idx = t + u * 256;
                wreg[u] = wd64p(o, (p + 1) * 32 + (idx >> 6))[idx & 63];
            }
            xreg = *(const float4*)(x + (((size_t)(b * 64 + (p + 1) * 2 + s_ciL) * 256 + (i * 4 + s_ky)) * 256 + jh * 128 + s_f4j * 4));
        }
        const double* wb = wlds[cur];
        const double* xb = xlds[cur];
        #pragma unroll
        for (int ciL = 0; ciL < 2; ++ciL) {
            #pragma unroll
            for (int ky = 0; ky < 4; ++ky) {
                int kq = ciL * 16 + ky * 4;
                double w_[4][4], x_[4][2];
                #pragma unroll
                for (int kx = 0; kx < 4; ++kx) {
                    const double* wp = wb + (kq + kx) * 64;
                    const double* xp = xb + (kq + kx) * 32;
                    double2 wa0 = *(const double2*)(wp + tc * 2);
                    double2 wa1 = *(const double2*)(wp + tc * 2 + 32);
                    double2 xa0 = *(const double2*)(xp + tj * 2);
                    w_[kx][0] = wa0.x; w_[kx][1] = wa0.y; w_[kx][2] = wa1.x; w_[kx][3] = wa1.y;
                    x_[kx][0] = xa0.x; x_[kx][1] = xa0.y;
                }
                #pragma unroll
                for (int c = 0; c < 4; ++c)
                    #pragma unroll
                    for (int jj = 0; jj < 2; ++jj)
                        acc[c][jj] = fma(w_[0][c], x_[0][jj],
                                     fma(w_[1][c], x_[1][jj],
                                     fma(w_[2][c], x_[2][jj],
                                     fma(w_[3][c], x_[3][jj], acc[c][jj]))));
            }
        }
        if (p + 1 < 32) {
            int nxt = (p + 1) & 1;
            #pragma unroll
            for (int u = 0; u < 8; ++u) {
                int idx = t + u * 256;
                wlds[nxt][(idx >> 6) * 64 + (idx & 63)] = wreg[u];
            }
            xlds[nxt][s_kq]      = (double)xreg.x;
            xlds[nxt][s_kq + 32] = (double)xreg.y;
            xlds[nxt][s_kq + 64] = (double)xreg.z;
            xlds[nxt][s_kq + 96] = (double)xreg.w;
            __syncthreads();
        }
    }
    #pragma unroll
    for (int c = 0; c < 4; ++c) {
        int co = ((c >> 1) << 5) + tc * 2 + (c & 1);
        double sc = (double)g[co] / sqrt((double)v[co] + 1e-5);
        double sh = (double)bd[co] - (double)m[co];
        double bb = (double)be[co];
        double o0v = fmax(0.0, (acc[c][0] + sh) * sc + bb);
        double o1v = fmax(0.0, (acc[c][1] + sh) * sc + bb);
        int pos0 = i * 64 + jh * 32 + tj * 2;
        float* cp = catp(o, b * 128 + co);
        *(float2*)(cp + pos0) = make_float2((float)o0v, (float)o1v);
        double* xh = x1hp(o, b * 64 + co);
        *(double2*)(xh + pos0) = make_double2(o0v, o1v);
    }
}

// ---------------- K2: windowed d^2 (f64, register-accumulated) -> top-9 -> f32 gather. block 512.
// 8 stages of 8 channels (R20-measured config).
__global__ __launch_bounds__(512) void k2_feat(float* __restrict__ o)
{
    __shared__ __align__(16) char smem[29568];   // tile_d[56][66] f64 | d2s[64*50] f64 | tileq[56][68] f32
    __shared__ double sqd[7 * 64];
    __shared__ int sels[64 * 9];
    double* tile_d = (double*)smem;
    double* d2s = (double*)smem;
    float* tileq = (float*)smem;
    int blk = blockIdx.x;
    int b = blk >> 6, i = blk & 63;
    int t = threadIdx.x;
    int lane = t & 63, wv = t >> 6;

    double dacc[7];
    #pragma unroll
    for (int k = 0; k < 7; ++k) dacc[k] = 0.0;
    double sq_own = 0.0;

    for (int q = 0; q < 8; ++q) {
        __syncthreads();
        for (int s = t; s < 1792; s += 512) {
            int rc = s >> 5, c2 = s & 31;
            int r = rc >> 3, c = rc & 7;
            int gr = i - 3 + r;
            if (gr >= 0 && gr <= 63) {
                const double* src = x1hp(o, b * 64 + q * 8 + c);
                *(double2*)(tile_d + rc * 66 + c2 * 2) = *(const double2*)(src + gr * 64 + c2 * 2);
            }
        }
        __syncthreads();
        if (t < 448) {
            int r = t >> 6, col = t & 63;
            int gr = i - 3 + r;
            if (gr >= 0 && gr <= 63) {
                double s = 0.0;
                #pragma unroll
                for (int c = 0; c < 8; ++c) {
                    double xv = tile_d[(r * 8 + c) * 66 + col];
                    s = fma(xv, xv, s);
                }
                sq_own += s;
            }
        }
        double xlq[8];
        #pragma unroll
        for (int c = 0; c < 8; ++c) xlq[c] = tile_d[(24 + c) * 66 + lane];
        #pragma unroll
        for (int k = 0; k < 7; ++k) {
            int oo = wv + 8 * k;
            if (oo < 49) {
                int oi = oo / 7 - 3, oj = oo % 7 - 3;
                int mi = i + oi, mj = lane + oj;
                if (mi >= 0 && mi <= 63 && mj >= 0 && mj <= 63) {
                    int r = oi + 3;
                    double dot = 0.0;
                    #pragma unroll
                    for (int c = 0; c < 8; ++c) dot = fma(xlq[c], tile_d[(r * 8 + c) * 66 + mj], dot);
                    dacc[k] += dot;
                }
            }
        }
    }
    __syncthreads();
    if (t < 448) sqd[t] = sq_own;
    __syncthreads();
    #pragma unroll
    for (int k = 0; k < 7; ++k) {
        int oo = wv + 8 * k;
        if (oo < 49) {
            int oi = oo / 7 - 3, oj = oo % 7 - 3;
            int mi = i + oi, mj = lane + oj;
            double d2 = -1e300;
            if (mi >= 0 && mi <= 63 && mj >= 0 && mj <= 63)
                d2 = sqd[192 + lane] + sqd[(oi + 3) * 64 + mj] - 2.0 * dacc[k];
            d2s[lane * 50 + oo] = d2;
        }
    }
    __syncthreads();
    if (wv == 0) {
        unsigned long long mask = 0ull;
        for (int k = 0; k < 9; ++k) {
            double best = -1e308; int bi = 0;
            for (int oo = 0; oo < 49; ++oo) {
                if ((mask >> oo) & 1ull) continue;
                double vv = d2s[lane * 50 + oo];
                if (vv > best) { best = vv; bi = oo; }
            }
            mask |= (1ull << bi);
            sels[lane * 9 + k] = bi;
        }
    }
    __syncthreads();
    int rk[9], cj[9];
    #pragma unroll
    for (int k = 0; k < 9; ++k) {
        int oo = sels[lane * 9 + k];
        rk[k] = oo / 7;
        cj[k] = lane + (oo % 7) - 3;
    }
    for (int q = 0; q < 8; ++q) {
        __syncthreads();
        for (int s = t; s < 896; s += 512) {
            int rc = s >> 4, x4 = s & 15;
            int r = rc >> 3, c = rc & 7;
            int gr = i - 3 + r;
            if (gr >= 0 && gr <= 63)
                *(float4*)(tileq + rc * 68 + x4 * 4) =
                    *(const float4*)(catp(o, b * 128 + q * 8 + c) + gr * 64 + x4 * 4);
        }
        __syncthreads();
        {
            int c = wv;
            float s = 0.f;
            #pragma unroll
            for (int k = 0; k < 9; ++k) s += tileq[(rk[k] * 8 + c) * 68 + cj[k]];
            float outv = s * (1.f / 9.f) - tileq[(24 + c) * 68 + lane];
            catp(o, b * 128 + 64 + q * 8 + c)[i * 64 + lane] = outv;
        }
    }
}

// ---------------- K3: 3x3 conv (128->64) + BN + ReLU, LDS-staged weights+inputs
// grid: 256 = B*64 rows; block 1024. LDS 49.5KB. 8 stages of 16 ci. (R20-measured 85us config.)
__global__ __launch_bounds__(1024) void k3_conv(
    float* __restrict__ o, const float* __restrict__ b1,
    const float* __restrict__ g, const float* __restrict__ be,
    const float* __restrict__ m, const float* __restrict__ v)
{
    __shared__ __align__(16) float wlds[16 * 9 * 64];
    __shared__ __align__(16) float xlds[3 * 16 * 72];
    int blk = blockIdx.x;
    int b = blk >> 6, i = blk & 63;
    int t = threadIdx.x;
    int co = t & 63, jg = t >> 6;
    float acc0 = 0.f, acc1 = 0.f, acc2 = 0.f, acc3 = 0.f;
    const float4 z4 = make_float4(0.f, 0.f, 0.f, 0.f);
    for (int st = 0; st < 8; ++st) {
        __syncthreads();
        for (int idx = t; idx < 9216; idx += 1024) {
            int kk = st * 144 + (idx >> 6);
            wlds[idx] = wtv(o, kk, idx & 63);
        }
        for (int f = t; f < 864; f += 1024) {
            int x4 = f % 18, rc = f / 18;
            int ry = rc >> 4, cl = rc & 15;
            int gr = i - 1 + ry;
            float4 val = z4;
            if (x4 >= 1 && x4 <= 16 && gr >= 0 && gr <= 63)
                val = *(const float4*)(catp(o, b * 128 + st * 16 + cl) + gr * 64 + (x4 - 1) * 4);
            *(float4*)(xlds + rc * 72 + x4 * 4) = val;
        }
        __syncthreads();
        for (int cl = 0; cl < 16; ++cl) {
            #pragma unroll
            for (int ry = 0; ry < 3; ++ry) {
                float w0  = wlds[(cl * 9 + ry * 3 + 0) * 64 + co];
                float w1f = wlds[(cl * 9 + ry * 3 + 1) * 64 + co];
                float w2  = wlds[(cl * 9 + ry * 3 + 2) * 64 + co];
                const float* xr = xlds + (ry * 16 + cl) * 72 + jg * 4;
                float4 q0 = *(const float4*)(xr);
                float4 q1 = *(const float4*)(xr + 4);
                float4 q2 = *(const float4*)(xr + 8);
                float xv[12] = { q0.x,q0.y,q0.z,q0.w, q1.x,q1.y,q1.z,q1.w, q2.x,q2.y,q2.z,q2.w };
                acc0 = fmaf(w0, xv[3], fmaf(w1f, xv[4], fmaf(w2, xv[5], acc0)));
                acc1 = fmaf(w0, xv[4], fmaf(w1f, xv[5], fmaf(w2, xv[6], acc1)));
                acc2 = fmaf(w0, xv[5], fmaf(w1f, xv[6], fmaf(w2, xv[7], acc2)));
                acc3 = fmaf(w0, xv[6], fmaf(w1f, xv[7], fmaf(w2, xv[8], acc3)));
            }
        }
    }
    float sc = g[co] * rsqrtf(v[co] + 1e-5f);
    float sh = b1[co] - m[co];
    float bb = be[co];
    float4 ov;
    ov.x = fmaxf(0.f, fmaf(acc0 + sh, sc, bb));
    ov.y = fmaxf(0.f, fmaf(acc1 + sh, sc, bb));
    ov.z = fmaxf(0.f, fmaf(acc2 + sh, sc, bb));
    ov.w = fmaxf(0.f, fmaf(acc3 + sh, sc, bb));
    *(float4*)(o + (size_t)(b * 64 + co) * 65536 + i * 64 + jg * 4) = ov;
}

// ---------------- K4a: per-plane spatial mean -> slot[12288]
__global__ __launch_bounds__(256) void k4_mean(float* __restrict__ o) {
    int q = blockIdx.x, t = threadIdx.x;
    const float* p = o + (size_t)q * 65536;
    float s = 0.f;
    for (int k = t; k < 4096; k += 256) s += p[k];
    #pragma unroll
    for (int off = 32; off > 0; off >>= 1) s += __shfl_down(s, off, 64);
    __shared__ float red[4];
    if ((t & 63) == 0) red[t >> 6] = s;
    __syncthreads();
    if (t == 0) o[(size_t)q * 65536 + 12288] = (red[0] + red[1] + red[2] + red[3]) * (1.f / 4096.f);
}

// ---------------- K5: att (1x1 conv + BN + sigmoid, per-block) + bilinear_x4 * att, in place.
__global__ __launch_bounds__(1024) void k5_up(float* __restrict__ o, const float* __restrict__ wa,
    const float* __restrict__ g, const float* __restrict__ be,
    const float* __restrict__ m, const float* __restrict__ v) {
    __shared__ __align__(16) float fplane[4096];
    __shared__ float att_s;
    int bc = blockIdx.x;
    int t = threadIdx.x;
    int b = bc >> 6, co = bc & 63;
    float* slot = o + (size_t)bc * 65536;
    *(float4*)(fplane + t * 4) = *(const float4*)(slot + t * 4);
    if (t < 64) {
        float s = wa[co * 64 + t] * o[(size_t)(b * 64 + t) * 65536 + 12288];
        #pragma unroll
        for (int off = 32; off > 0; off >>= 1) s += __shfl_down(s, off, 64);
        if (t == 0) {
            float sc = g[co] * rsqrtf(v[co] + 1e-5f);
            float y = fmaf(s - m[co], sc, be[co]);
            att_s = 1.f / (1.f + expf(-y));
        }
    }
    __syncthreads();
    float att = att_s;
    int ox = t & 255, oyc = t >> 8;
    float fx = ox * 0.25f - 0.375f;
    int ix = (int)floorf(fx);
    float wx = fx - (float)ix;
    int x0 = ix < 0 ? 0 : ix;
    int x1 = (ix + 1 > 63) ? 63 : ix + 1;
    for (int oy = oyc * 64; oy < oyc * 64 + 64; ++oy) {
        float fy = oy * 0.25f - 0.375f;
        int iy = (int)floorf(fy);
        float wy = fy - (float)iy;
        int y0 = iy < 0 ? 0 : iy;
        int y1 = (iy + 1 > 63) ? 63 : iy + 1;
        float a  = fplane[y0 * 64 + x0], b_ = fplane[y0 * 64 + x1];
        float c_ = fplane[y1 * 64 + x0], d_ = fplane[y1 * 64 + x1];
        float top = a + wx * (b_ - a);
        float bot = c_ + wx * (d_ - c_);
        float val = (top + wy * (bot - top)) * att;
        slot[oy * 256 + ox] = val;
    }
}

extern "C" void kernel_launch(void* const* d_in, const int* in_sizes, int n_in,
                              void* d_out, int out_size, void* d_ws, size_t ws_size,
                              hipStream_t stream) {
    const float* x     = (const float*)d_in[0];
    const float* wd    = (const float*)d_in[1];
    const float* bd    = (const float*)d_in[2];
    const float* bnd_g = (const float*)d_in[3];
    const float* bnd_b = (const float*)d_in[4];
    const float* bnd_m = (const float*)d_in[5];
    const float* bnd_v = (const float*)d_in[6];
    const float* w1    = (const float*)d_in[7];
    const float* b1    = (const float*)d_in[8];
    const float* bn1_g = (const float*)d_in[9];
    const float* bn1_b = (const float*)d_in[10];
    const float* bn1_m = (const float*)d_in[11];
    const float* bn1_v = (const float*)d_in[12];
    const float* wa    = (const float*)d_in[13];
    const float* bna_g = (const float*)d_in[14];
    const float* bna_b = (const float*)d_in[15];
    const float* bna_m = (const float*)d_in[16];
    const float* bna_v = (const float*)d_in[17];

    float* o = (float*)d_out;

    hipLaunchKernelGGL(k0_wtrans, dim3(544), dim3(256), 0, stream, w1, wd, o);
    hipLaunchKernelGGL(k1_convds, dim3(512), dim3(256), 0, stream,
                       x, bd, bnd_g, bnd_b, bnd_m, bnd_v, o);
    hipLaunchKernelGGL(k2_feat, dim3(256), dim3(512), 0, stream, o);
    hipLaunchKernelGGL(k3_conv, dim3(256), dim3(1024), 0, stream,
                       o, b1, bn1_g, bn1_b, bn1_m, bn1_v);
    hipLaunchKernelGGL(k4_mean, dim3(256), dim3(256), 0, stream, o);
    hipLaunchKernelGGL(k5_up, dim3(256), dim3(1024), 0, stream,
                       o, wa, bna_g, bna_b, bna_m, bna_v);
}

// Round 25
// 231.383 us; speedup vs baseline: 1.2234x; 1.0192x over previous
//
#include <hip/hip_runtime.h>
#include <hip/hip_bf16.h>
#include <stdint.h>

// ---- All intermediates live inside d_out (16,777,216 f32; 256 slots x 65536 f32).
// Slot q (q=b*64+co): [0,4096) feat plane q ; [4096,8192) cat plane p (p<256, p&255==q)
// [8192,12288) cat plane p (p>=256) ; [13312,13376) rowsum[q][i] ;
// [16384,24576) f64 x1_hi plane q ; [25600,26112) wT chunks ; [26624,27136) wdT64 chunks (f64).
__device__ __forceinline__ float* catp(float* o, int p) {
    return o + (size_t)(p & 255) * 65536 + 4096 + ((p >> 8) << 12);
}
__device__ __forceinline__ double* x1hp(float* o, int q) {
    return (double*)(o + (size_t)q * 65536 + 16384);
}
__device__ __forceinline__ float wtv(const float* o, int kk, int co) {
    return o[(size_t)(kk >> 3) * 65536 + 25600 + (kk & 7) * 64 + co];
}
__device__ __forceinline__ double* wd64p(float* o, int k) {   // + co
    return (double*)(o + (size_t)(k >> 2) * 65536 + 26624) + (k & 3) * 64;
}

// ---------------- K0: w1 -> wT[kk][co] (f32); wd -> wdT64[k][co] (f64)
__global__ __launch_bounds__(256) void k0_wtrans(const float* __restrict__ w1, const float* __restrict__ wd,
                                                 float* __restrict__ o) {
    int idx = blockIdx.x * 256 + threadIdx.x;
    if (idx < 73728) {
        int co = idx & 63, kk = idx >> 6;
        o[(size_t)(kk >> 3) * 65536 + 25600 + (kk & 7) * 64 + co] = w1[co * 1152 + kk];
    } else if (idx < 139264) {
        int j = idx - 73728;
        int co = j & 63, k = j >> 6;
        wd64p(o, k)[co] = (double)wd[co * 1024 + k];
    }
}

// ---------------- K1: 4x4/stride-4 conv + BN + ReLU as f64 register-blocked GEMM
// grid: 512 = (b,i,jh); block 256; thread = 4co x 2j. Double-buffered LDS (48KB) +
// register prefetch; ONE barrier/panel. Bit-identical outputs.
__global__ __launch_bounds__(256) void k1_convds(
    const float* __restrict__ x, const float* __restrict__ bd,
    const float* __restrict__ g, const float* __restrict__ be,
    const float* __restrict__ m, const float* __restrict__ v,
    float* __restrict__ o)
{
    __shared__ __align__(16) double wlds[2][32 * 64];
    __shared__ __align__(16) double xlds[2][32 * 32];
    int blk = blockIdx.x;
    int jh = blk & 1, i = (blk >> 1) & 63, b = blk >> 7;
    int t = threadIdx.x;
    int tj = t & 15, tc = t >> 4;
    int s_f4j = t & 31, s_ky = (t >> 5) & 3, s_ciL = t >> 7;
    int s_kq = (s_ciL * 16 + s_ky * 4) * 32 + s_f4j;

    double acc[4][2];
    #pragma unroll
    for (int c = 0; c < 4; ++c) { acc[c][0] = 0.0; acc[c][1] = 0.0; }

    double wreg[8];
    float4 xreg;
    #pragma unroll
    for (int u = 0; u < 8; ++u) {
        int idx = t + u * 256;
        wreg[u] = wd64p(o, (idx >> 6))[idx & 63];
    }
    xreg = *(const float4*)(x + (((size_t)(b * 64 + s_ciL) * 256 + (i * 4 + s_ky)) * 256 + jh * 128 + s_f4j * 4));
    #pragma unroll
    for (int u = 0; u < 8; ++u) {
        int idx = t + u * 256;
        wlds[0][(idx >> 6) * 64 + (idx & 63)] = wreg[u];
    }
    xlds[0][s_kq]      = (double)xreg.x;
    xlds[0][s_kq + 32] = (double)xreg.y;
    xlds[0][s_kq + 64] = (double)xreg.z;
    xlds[0][s_kq + 96] = (double)xreg.w;
    __syncthreads();

    for (int p = 0; p < 32; ++p) {
        int cur = p & 1;
        if (p + 1 < 32) {
            #pragma unroll
            for (int u = 0; u < 8; ++u) {
                int idx = t + u * 256;
                wreg[u] = wd64p(o, (p + 1) * 32 + (idx >> 6))[idx & 63];
            }
            xreg = *(const float4*)(x + (((size_t)(b * 64 + (p + 1) * 2 + s_ciL) * 256 + (i * 4 + s_ky)) * 256 + jh * 128 + s_f4j * 4));
        }
        const double* wb = wlds[cur];
        const double* xb = xlds[cur];
        #pragma unroll
        for (int ciL = 0; ciL < 2; ++ciL) {
            #pragma unroll
            for (int ky = 0; ky < 4; ++ky) {
                int kq = ciL * 16 + ky * 4;
                double w_[4][4], x_[4][2];
                #pragma unroll
                for (int kx = 0; kx < 4; ++kx) {
                    const double* wp = wb + (kq + kx) * 64;
                    const double* xp = xb + (kq + kx) * 32;
                    double2 wa0 = *(const double2*)(wp + tc * 2);
                    double2 wa1 = *(const double2*)(wp + tc * 2 + 32);
                    double2 xa0 = *(const double2*)(xp + tj * 2);
                    w_[kx][0] = wa0.x; w_[kx][1] = wa0.y; w_[kx][2] = wa1.x; w_[kx][3] = wa1.y;
                    x_[kx][0] = xa0.x; x_[kx][1] = xa0.y;
                }
                #pragma unroll
                for (int c = 0; c < 4; ++c)
                    #pragma unroll
                    for (int jj = 0; jj < 2; ++jj)
                        acc[c][jj] = fma(w_[0][c], x_[0][jj],
                                     fma(w_[1][c], x_[1][jj],
                                     fma(w_[2][c], x_[2][jj],
                                     fma(w_[3][c], x_[3][jj], acc[c][jj]))));
            }
        }
        if (p + 1 < 32) {
            int nxt = (p + 1) & 1;
            #pragma unroll
            for (int u = 0; u < 8; ++u) {
                int idx = t + u * 256;
                wlds[nxt][(idx >> 6) * 64 + (idx & 63)] = wreg[u];
            }
            xlds[nxt][s_kq]      = (double)xreg.x;
            xlds[nxt][s_kq + 32] = (double)xreg.y;
            xlds[nxt][s_kq + 64] = (double)xreg.z;
            xlds[nxt][s_kq + 96] = (double)xreg.w;
            __syncthreads();
        }
    }
    #pragma unroll
    for (int c = 0; c < 4; ++c) {
        int co = ((c >> 1) << 5) + tc * 2 + (c & 1);
        double sc = (double)g[co] / sqrt((double)v[co] + 1e-5);
        double sh = (double)bd[co] - (double)m[co];
        double bb = (double)be[co];
        double o0v = fmax(0.0, (acc[c][0] + sh) * sc + bb);
        double o1v = fmax(0.0, (acc[c][1] + sh) * sc + bb);
        int pos0 = i * 64 + jh * 32 + tj * 2;
        float* cp = catp(o, b * 128 + co);
        *(float2*)(cp + pos0) = make_float2((float)o0v, (float)o1v);
        double* xh = x1hp(o, b * 64 + co);
        *(double2*)(xh + pos0) = make_double2(o0v, o1v);
    }
}

// ---------------- K2: windowed d^2 (f64, register-accumulated) -> top-9 -> f32 gather. block 512.
__global__ __launch_bounds__(512) void k2_feat(float* __restrict__ o)
{
    __shared__ __align__(16) char smem[29568];   // tile_d[56][66] f64 | d2s[64*50] f64 | tileq[56][68] f32
    __shared__ double sqd[7 * 64];
    __shared__ int sels[64 * 9];
    double* tile_d = (double*)smem;
    double* d2s = (double*)smem;
    float* tileq = (float*)smem;
    int blk = blockIdx.x;
    int b = blk >> 6, i = blk & 63;
    int t = threadIdx.x;
    int lane = t & 63, wv = t >> 6;

    double dacc[7];
    #pragma unroll
    for (int k = 0; k < 7; ++k) dacc[k] = 0.0;
    double sq_own = 0.0;

    for (int q = 0; q < 8; ++q) {
        __syncthreads();
        for (int s = t; s < 1792; s += 512) {
            int rc = s >> 5, c2 = s & 31;
            int r = rc >> 3, c = rc & 7;
            int gr = i - 3 + r;
            if (gr >= 0 && gr <= 63) {
                const double* src = x1hp(o, b * 64 + q * 8 + c);
                *(double2*)(tile_d + rc * 66 + c2 * 2) = *(const double2*)(src + gr * 64 + c2 * 2);
            }
        }
        __syncthreads();
        if (t < 448) {
            int r = t >> 6, col = t & 63;
            int gr = i - 3 + r;
            if (gr >= 0 && gr <= 63) {
                double s = 0.0;
                #pragma unroll
                for (int c = 0; c < 8; ++c) {
                    double xv = tile_d[(r * 8 + c) * 66 + col];
                    s = fma(xv, xv, s);
                }
                sq_own += s;
            }
        }
        double xlq[8];
        #pragma unroll
        for (int c = 0; c < 8; ++c) xlq[c] = tile_d[(24 + c) * 66 + lane];
        #pragma unroll
        for (int k = 0; k < 7; ++k) {
            int oo = wv + 8 * k;
            if (oo < 49) {
                int oi = oo / 7 - 3, oj = oo % 7 - 3;
                int mi = i + oi, mj = lane + oj;
                if (mi >= 0 && mi <= 63 && mj >= 0 && mj <= 63) {
                    int r = oi + 3;
                    double dot = 0.0;
                    #pragma unroll
                    for (int c = 0; c < 8; ++c) dot = fma(xlq[c], tile_d[(r * 8 + c) * 66 + mj], dot);
                    dacc[k] += dot;
                }
            }
        }
    }
    __syncthreads();
    if (t < 448) sqd[t] = sq_own;
    __syncthreads();
    #pragma unroll
    for (int k = 0; k < 7; ++k) {
        int oo = wv + 8 * k;
        if (oo < 49) {
            int oi = oo / 7 - 3, oj = oo % 7 - 3;
            int mi = i + oi, mj = lane + oj;
            double d2 = -1e300;
            if (mi >= 0 && mi <= 63 && mj >= 0 && mj <= 63)
                d2 = sqd[192 + lane] + sqd[(oi + 3) * 64 + mj] - 2.0 * dacc[k];
            d2s[lane * 50 + oo] = d2;
        }
    }
    __syncthreads();
    if (wv == 0) {
        unsigned long long mask = 0ull;
        for (int k = 0; k < 9; ++k) {
            double best = -1e308; int bi = 0;
            for (int oo = 0; oo < 49; ++oo) {
                if ((mask >> oo) & 1ull) continue;
                double vv = d2s[lane * 50 + oo];
                if (vv > best) { best = vv; bi = oo; }
            }
            mask |= (1ull << bi);
            sels[lane * 9 + k] = bi;
        }
    }
    __syncthreads();
    int rk[9], cj[9];
    #pragma unroll
    for (int k = 0; k < 9; ++k) {
        int oo = sels[lane * 9 + k];
        rk[k] = oo / 7;
        cj[k] = lane + (oo % 7) - 3;
    }
    for (int q = 0; q < 8; ++q) {
        __syncthreads();
        for (int s = t; s < 896; s += 512) {
            int rc = s >> 4, x4 = s & 15;
            int r = rc >> 3, c = rc & 7;
            int gr = i - 3 + r;
            if (gr >= 0 && gr <= 63)
                *(float4*)(tileq + rc * 68 + x4 * 4) =
                    *(const float4*)(catp(o, b * 128 + q * 8 + c) + gr * 64 + x4 * 4);
        }
        __syncthreads();
        {
            int c = wv;
            float s = 0.f;
            #pragma unroll
            for (int k = 0; k < 9; ++k) s += tileq[(rk[k] * 8 + c) * 68 + cj[k]];
            float outv = s * (1.f / 9.f) - tileq[(24 + c) * 68 + lane];
            catp(o, b * 128 + 64 + q * 8 + c)[i * 64 + lane] = outv;
        }
    }
}

// ---------------- K3: 3x3 conv (128->64) + BN + ReLU + per-row feat sums -> rowsum[q][i]
// grid: 256 = B*64 rows; block 1024. LDS 49.5KB. 8 stages of 16 ci.
__global__ __launch_bounds__(1024) void k3_conv(
    float* __restrict__ o, const float* __restrict__ b1,
    const float* __restrict__ g, const float* __restrict__ be,
    const float* __restrict__ m, const float* __restrict__ v)
{
    __shared__ __align__(16) float wlds[16 * 9 * 64];
    __shared__ __align__(16) float xlds[3 * 16 * 72];
    int blk = blockIdx.x;
    int b = blk >> 6, i = blk & 63;
    int t = threadIdx.x;
    int co = t & 63, jg = t >> 6;
    float acc0 = 0.f, acc1 = 0.f, acc2 = 0.f, acc3 = 0.f;
    const float4 z4 = make_float4(0.f, 0.f, 0.f, 0.f);
    for (int st = 0; st < 8; ++st) {
        __syncthreads();
        for (int idx = t; idx < 9216; idx += 1024) {
            int kk = st * 144 + (idx >> 6);
            wlds[idx] = wtv(o, kk, idx & 63);
        }
        for (int f = t; f < 864; f += 1024) {
            int x4 = f % 18, rc = f / 18;
            int ry = rc >> 4, cl = rc & 15;
            int gr = i - 1 + ry;
            float4 val = z4;
            if (x4 >= 1 && x4 <= 16 && gr >= 0 && gr <= 63)
                val = *(const float4*)(catp(o, b * 128 + st * 16 + cl) + gr * 64 + (x4 - 1) * 4);
            *(float4*)(xlds + rc * 72 + x4 * 4) = val;
        }
        __syncthreads();
        for (int cl = 0; cl < 16; ++cl) {
            #pragma unroll
            for (int ry = 0; ry < 3; ++ry) {
                float w0  = wlds[(cl * 9 + ry * 3 + 0) * 64 + co];
                float w1f = wlds[(cl * 9 + ry * 3 + 1) * 64 + co];
                float w2  = wlds[(cl * 9 + ry * 3 + 2) * 64 + co];
                const float* xr = xlds + (ry * 16 + cl) * 72 + jg * 4;
                float4 q0 = *(const float4*)(xr);
                float4 q1 = *(const float4*)(xr + 4);
                float4 q2 = *(const float4*)(xr + 8);
                float xv[12] = { q0.x,q0.y,q0.z,q0.w, q1.x,q1.y,q1.z,q1.w, q2.x,q2.y,q2.z,q2.w };
                acc0 = fmaf(w0, xv[3], fmaf(w1f, xv[4], fmaf(w2, xv[5], acc0)));
                acc1 = fmaf(w0, xv[4], fmaf(w1f, xv[5], fmaf(w2, xv[6], acc1)));
                acc2 = fmaf(w0, xv[5], fmaf(w1f, xv[6], fmaf(w2, xv[7], acc2)));
                acc3 = fmaf(w0, xv[6], fmaf(w1f, xv[7], fmaf(w2, xv[8], acc3)));
            }
        }
    }
    float sc = g[co] * rsqrtf(v[co] + 1e-5f);
    float sh = b1[co] - m[co];
    float bb = be[co];
    float4 ov;
    ov.x = fmaxf(0.f, fmaf(acc0 + sh, sc, bb));
    ov.y = fmaxf(0.f, fmaf(acc1 + sh, sc, bb));
    ov.z = fmaxf(0.f, fmaf(acc2 + sh, sc, bb));
    ov.w = fmaxf(0.f, fmaf(acc3 + sh, sc, bb));
    *(float4*)(o + (size_t)(b * 64 + co) * 65536 + i * 64 + jg * 4) = ov;
    // per-row plane sums -> rowsum[b*64+co][i] (replaces k4_mean)
    float sloc = ov.x + ov.y + ov.z + ov.w;
    __syncthreads();                       // all LDS reads of last stage complete
    xlds[jg * 64 + co] = sloc;
    __syncthreads();
    if (t < 64) {
        float r = 0.f;
        #pragma unroll
        for (int j = 0; j < 16; ++j) r += xlds[j * 64 + t];
        o[(size_t)(b * 64 + t) * 65536 + 13312 + i] = r;
    }
}

// ---------------- K5: att (mean from rowsums + 1x1 conv + BN + sigmoid) + bilinear_x4 * att.
__global__ __launch_bounds__(1024) void k5_up(float* __restrict__ o, const float* __restrict__ wa,
    const float* __restrict__ g, const float* __restrict__ be,
    const float* __restrict__ m, const float* __restrict__ v) {
    __shared__ __align__(16) float fplane[4096];
    __shared__ float att_s;
    int bc = blockIdx.x;
    int t = threadIdx.x;
    int b = bc >> 6, co = bc & 63;
    float* slot = o + (size_t)bc * 65536;
    *(float4*)(fplane + t * 4) = *(const float4*)(slot + t * 4);
    if (t < 64) {
        const float* rs = o + (size_t)(b * 64 + t) * 65536 + 13312;
        float m_ = 0.f;
        #pragma unroll
        for (int j = 0; j < 16; ++j) {
            float4 v4 = *(const float4*)(rs + j * 4);
            m_ += v4.x + v4.y + v4.z + v4.w;
        }
        float s = wa[co * 64 + t] * (m_ * (1.f / 4096.f));
        #pragma unroll
        for (int off = 32; off > 0; off >>= 1) s += __shfl_down(s, off, 64);
        if (t == 0) {
            float sc = g[co] * rsqrtf(v[co] + 1e-5f);
            float y = fmaf(s - m[co], sc, be[co]);
            att_s = 1.f / (1.f + expf(-y));
        }
    }
    __syncthreads();
    float att = att_s;
    int ox = t & 255, oyc = t >> 8;
    float fx = ox * 0.25f - 0.375f;
    int ix = (int)floorf(fx);
    float wx = fx - (float)ix;
    int x0 = ix < 0 ? 0 : ix;
    int x1 = (ix + 1 > 63) ? 63 : ix + 1;
    for (int oy = oyc * 64; oy < oyc * 64 + 64; ++oy) {
        float fy = oy * 0.25f - 0.375f;
        int iy = (int)floorf(fy);
        float wy = fy - (float)iy;
        int y0 = iy < 0 ? 0 : iy;
        int y1 = (iy + 1 > 63) ? 63 : iy + 1;
        float a  = fplane[y0 * 64 + x0], b_ = fplane[y0 * 64 + x1];
        float c_ = fplane[y1 * 64 + x0], d_ = fplane[y1 * 64 + x1];
        float top = a + wx * (b_ - a);
        float bot = c_ + wx * (d_ - c_);
        float val = (top + wy * (bot - top)) * att;
        slot[oy * 256 + ox] = val;
    }
}

extern "C" void kernel_launch(void* const* d_in, const int* in_sizes, int n_in,
                              void* d_out, int out_size, void* d_ws, size_t ws_size,
                              hipStream_t stream) {
    const float* x     = (const float*)d_in[0];
    const float* wd    = (const float*)d_in[1];
    const float* bd    = (const float*)d_in[2];
    const float* bnd_g = (const float*)d_in[3];
    const float* bnd_b = (const float*)d_in[4];
    const float* bnd_m = (const float*)d_in[5];
    const float* bnd_v = (const float*)d_in[6];
    const float* w1    = (const float*)d_in[7];
    const float* b1    = (const float*)d_in[8];
    const float* bn1_g = (const float*)d_in[9];
    const float* bn1_b = (const float*)d_in[10];
    const float* bn1_m = (const float*)d_in[11];
    const float* bn1_v = (const float*)d_in[12];
    const float* wa    = (const float*)d_in[13];
    const float* bna_g = (const float*)d_in[14];
    const float* bna_b = (const float*)d_in[15];
    const float* bna_m = (const float*)d_in[16];
    const float* bna_v = (const float*)d_in[17];

    float* o = (float*)d_out;

    hipLaunchKernelGGL(k0_wtrans, dim3(544), dim3(256), 0, stream, w1, wd, o);
    hipLaunchKernelGGL(k1_convds, dim3(512), dim3(256), 0, stream,
                       x, bd, bnd_g, bnd_b, bnd_m, bnd_v, o);
    hipLaunchKernelGGL(k2_feat, dim3(256), dim3(512), 0, stream, o);
    hipLaunchKernelGGL(k3_conv, dim3(256), dim3(1024), 0, stream,
                       o, b1, bn1_g, bn1_b, bn1_m, bn1_v);
    hipLaunchKernelGGL(k5_up, dim3(256), dim3(1024), 0, stream,
                       o, wa, bna_g, bna_b, bna_m, bna_v);
}